// Round 7
// baseline (461.603 us; speedup 1.0000x reference)
//
#include <hip/hip_runtime.h>
#include <math.h>

// ---------------- problem constants ----------------
#define NS 612
#define NECOL 216
#define BATCH 32
#define TLEN 2048
#define ROWW 1040                // permuted emission row stride (floats)
#define CE 2.7182818284590452f

// ---------------- ws layout (float offsets) ----------------
#define O_AV0 0                  // [101] match-entry coef  exp(w[1+i])/Z3[i]
#define O_AV1 128                // [101] insert-exit coef  exp(w[203+i])/Z310[i]
#define O_BV0 256                // [101] insert-entry coef exp(w[101+i])/Z3[i]
#define O_BV1 384                // [101] insert-keep coef  exp(1-w[203+i])/Z310[i]
#define O_IZ3 512                // [101] 1/Z3[i]
#define O_SC  640                // [0]=wk [1]=A00 [2]=A01
#define O_PIP 768                // [1040] permuted softmax(init)
#define O_ET  2048               // [216*1040] permuted E^T rows

// pair-interleaved slot map (verified round 6, absmax 0):
//  row floats [0..5]  = specials {0,1,2,3,307,611}
//  row floats [16+L*16 + 0..2]  codon i=2L   | [+4..6]  insert i=2L
//              [+8..10]          codon i=2L+1 | [+12..14] insert i=2L+1
__device__ __forceinline__ int eslot(int s) {
  if (s >= 4 && s <= 306)  { int i = (s - 4) / 3,  r = (s - 4) % 3;
    return 16 + (i >> 1) * 16 + (i & 1) * 8 + r; }
  if (s >= 308 && s <= 610){ int i = (s - 308) / 3, r = (s - 308) % 3;
    return 16 + (i >> 1) * 16 + (i & 1) * 8 + 4 + r; }
  if (s <= 3)   return s;
  if (s == 307) return 4;
  return 5;   // s == 611
}

__device__ __forceinline__ float ipowf(float r, int k) {
  float res = 1.f, bse = r;
  #pragma unroll
  for (int q = 0; q < 7; ++q) { if (k & 1) res *= bse; bse *= bse; k >>= 1; }
  return res;
}

// ---------------- DPP helpers ----------------
#define DPPF(x, ctrl, rm) __int_as_float(__builtin_amdgcn_update_dpp(0, __float_as_int(x), (ctrl), (rm), 0xf, true))

__device__ __forceinline__ float scan_plain(float x) {
  x += DPPF(x, 0x111, 0xf);
  x += DPPF(x, 0x112, 0xf);
  x += DPPF(x, 0x114, 0xf);
  x += DPPF(x, 0x118, 0xf);
  x += DPPF(x, 0x142, 0xa);
  x += DPPF(x, 0x143, 0xc);
  return x;
}
__device__ __forceinline__ float scan_atten(float x, float q1, float q2, float q4, float q8,
                                            float fA, float fB) {
  x = fmaf(DPPF(x, 0x111, 0xf), q1, x);
  x = fmaf(DPPF(x, 0x112, 0xf), q2, x);
  x = fmaf(DPPF(x, 0x114, 0xf), q4, x);
  x = fmaf(DPPF(x, 0x118, 0xf), q8, x);
  x = fmaf(DPPF(x, 0x142, 0xa), fA, x);
  x = fmaf(DPPF(x, 0x143, 0xc), fB, x);
  return x;
}
__device__ __forceinline__ float wshr1(float x) { return DPPF(x, 0x138, 0xf); }
__device__ __forceinline__ float rdl(float x, int l) {
  return __int_as_float(__builtin_amdgcn_readlane(__float_as_int(x), l));
}

// ---------------- prep: coefficient tables (math unchanged, verified) -------
__global__ void k_prep(const float* __restrict__ w, float* __restrict__ ws) {
  __shared__ float Gs[101];
  int tid = threadIdx.x;                  // 128
  float wk = w[304];
  if (tid >= 1 && tid <= 100) {
    float p = wk;
    for (int k = 0; k < tid; ++k) p *= wk;
    Gs[tid] = expf(1.f - p);
  }
  if (tid == 0) {
    Gs[0] = 0.f;
    ws[O_SC + 0] = wk;
    float Z0 = expf(1.f - w[0]) + expf(w[0]);
    ws[O_SC + 1] = expf(1.f - w[0]) / Z0;
    ws[O_SC + 2] = expf(w[0]) / Z0;
  }
  __syncthreads();
  if (tid <= 100) {
    float em = expf(w[tid < 100 ? 1 + tid : 202]);
    float ei = expf(w[101 + tid]);
    float z = em + ei;
    for (int d = 1; d <= 100 - tid; ++d) z += Gs[d];
    float ex = expf(w[203 + tid]);
    float es = expf(1.f - w[203 + tid]);
    float z310 = ex + es;
    ws[O_AV0 + tid] = em / z;
    ws[O_BV0 + tid] = ei / z;
    ws[O_AV1 + tid] = ex / z310;
    ws[O_BV1 + tid] = es / z310;
    ws[O_IZ3 + tid] = 1.f / z;
  }
}

// zero-fill all Et rows (unmapped slots must be 0 — lanes multiply them blindly)
__global__ void k_zr(float* __restrict__ ws) {
  float* row = ws + O_ET + (size_t)blockIdx.x * ROWW;
  for (int i = threadIdx.x; i < ROWW; i += 256) row[i] = 0.f;
}

__global__ void k_et(const float* __restrict__ ek, float* __restrict__ ws) {
  float* Etp = ws + O_ET;
  int s = blockIdx.x;
  int lane = threadIdx.x;                 // 64
  int sl = eslot(s);
  float x[4]; float m = -1e30f;
  #pragma unroll
  for (int k = 0; k < 4; ++k) {
    int c = lane + 64 * k;
    x[k] = (c < NECOL) ? ek[s * NECOL + c] : -1e30f;
    m = fmaxf(m, x[k]);
  }
  #pragma unroll
  for (int o = 32; o; o >>= 1) m = fmaxf(m, __shfl_xor(m, o, 64));
  float e[4]; float sum = 0.f;
  #pragma unroll
  for (int k = 0; k < 4; ++k) {
    int c = lane + 64 * k;
    e[k] = (c < NECOL) ? expf(x[k] - m) : 0.f;
    sum += e[k];
  }
  #pragma unroll
  for (int o = 32; o; o >>= 1) sum += __shfl_xor(sum, o, 64);
  float inv = 1.f / sum;
  #pragma unroll
  for (int k = 0; k < 4; ++k) {
    int c = lane + 64 * k;
    if (c < NECOL) Etp[(size_t)c * ROWW + sl] = e[k] * inv;
  }
}

__global__ void k_pi(const float* __restrict__ ik, float* __restrict__ ws) {
  float* pip = ws + O_PIP;
  __shared__ float wm[10], wsm[10];
  int tid = threadIdx.x;                  // 640
  for (int i = tid; i < ROWW; i += 640) pip[i] = 0.f;
  __syncthreads();
  int lane = tid & 63, wid = tid >> 6;
  float x = (tid < NS) ? ik[tid] : -1e30f;
  float m = x;
  #pragma unroll
  for (int o = 32; o; o >>= 1) m = fmaxf(m, __shfl_xor(m, o, 64));
  if (lane == 0) wm[wid] = m;
  __syncthreads();
  float mm = wm[0];
  #pragma unroll
  for (int k = 1; k < 10; ++k) mm = fmaxf(mm, wm[k]);
  float e = (tid < NS) ? expf(x - mm) : 0.f;
  float sacc = e;
  #pragma unroll
  for (int o = 32; o; o >>= 1) sacc += __shfl_xor(sacc, o, 64);
  if (lane == 0) wsm[wid] = sacc;
  __syncthreads();
  float ss = 0.f;
  #pragma unroll
  for (int k = 0; k < 10; ++k) ss += wsm[k];
  if (tid < NS) pip[eslot(tid)] = e / ss;
}

// ---------------- main: one WAVE per sequence, pair-interleaved, no LDS -----
// __launch_bounds__(64, 1): 1 wave/EU target -> full VGPR budget, so depth-3
// prefetch slots stay register-resident (pressure-driven load sinking killed
// the pipeline at VGPR=40 in round 6).
__global__ __launch_bounds__(64, 1) void k_main(const int* __restrict__ ids,
                                                const float* __restrict__ ws,
                                                float* __restrict__ out) {
  const int L = threadIdx.x, b = blockIdx.x;
  const int* idsb = ids + b * TLEN;
  const float* Etp = ws + O_ET;
  const float* pip = ws + O_PIP;

  // per-lane coefficient indices (clamped; invalid lanes neutralized by E=0)
  int ie = 2 * L;     if (ie > 100) ie = 100;
  int io = 2 * L + 1; if (io > 100) io = 100;
  float AV0e = ws[O_AV0 + ie], AV1e = ws[O_AV1 + ie];
  float BV0e = ws[O_BV0 + ie], BV1e = ws[O_BV1 + ie];
  float AV0o = ws[O_AV0 + io], AV1o = ws[O_AV1 + io];
  float BV0o = ws[O_BV0 + io], BV1o = ws[O_BV1 + io];
  float ize = (2 * L <= 99)     ? ws[O_IZ3 + 2 * L]     : 0.f;
  float izo = (2 * L + 1 <= 99) ? ws[O_IZ3 + 2 * L + 1] : 0.f;
  float wk  = ws[O_SC + 0], A00 = ws[O_SC + 1], A01 = ws[O_SC + 2];

  const bool isL0 = (L == 0);
  const float sk1 = 1.f - wk;
  const float r2 = wk * wk;                       // pair-step ratio
  const float q1 = r2, q2 = q1 * q1, q4 = q2 * q2, q8 = q4 * q4;
  const float fA = ipowf(r2, (L & 15) + 1), fB = ipowf(r2, (L & 31) + 1);

  const int loff = 16 + L * 16;

  // ---- t = 0: beta = pi * Et[obs0] ----
  int ob0 = __builtin_amdgcn_readfirstlane(idsb[0]);
  const float* R0 = Etp + (size_t)ob0 * ROWW;
  float4 pce = *(const float4*)(pip + loff);
  float4 pie = *(const float4*)(pip + loff + 4);
  float4 pco = *(const float4*)(pip + loff + 8);
  float4 pio = *(const float4*)(pip + loff + 12);
  float4 ps4 = *(const float4*)(pip + 0);
  float2 ps2 = *(const float2*)(pip + 4);
  float4 Ea = *(const float4*)(R0 + loff);
  float4 Eb = *(const float4*)(R0 + loff + 4);
  float4 Ec = *(const float4*)(R0 + loff + 8);
  float4 Ed = *(const float4*)(R0 + loff + 12);
  float4 Es4 = *(const float4*)(R0 + 0);
  float2 Es2 = *(const float2*)(R0 + 4);

  float c4e = pce.x * Ea.x, c5e = pce.y * Ea.y, c6e = pce.z * Ea.z;
  float i8e = pie.x * Eb.x, i9e = pie.y * Eb.y, i10e = pie.z * Eb.z;
  float c4o = pco.x * Ec.x, c5o = pco.y * Ec.y, c6o = pco.z * Ec.z;
  float i8o = pio.x * Ed.x, i9o = pio.y * Ed.y, i10o = pio.z * Ed.z;
  float a0 = ps4.x * Es4.x, a1 = ps4.y * Es4.y, a2 = ps4.z * Es4.z, a3 = ps4.w * Es4.w;
  float a307 = ps2.x * Es2.x, a611 = ps2.y * Es2.y;

  // initial md + scans (feed D at t=1)
  float mde, mdo, I0e, I0o, I1e, I1o;
  {
    float pme = wshr1(c6o); pme = isL0 ? a3 : pme;
    mde = pme * ize;
    mdo = c6e * izo;
    float v0 = mde + mdo;
    float S = scan_plain(v0);
    I0o = S; I0e = wshr1(S) + mde;
    float v1 = fmaf(wk, mde, mdo);
    float T = scan_atten(v1, q1, q2, q4, q8, fA, fB);
    I1o = T; I1e = fmaf(wk, wshr1(T), mde);
  }

  int e_acc = 0;

#define STEP_BODY(Ca, Cb, Cc, Cd, Cs4, Cs2) do { \
    float cbE = fmaf(-wk, I1e, I0e); cbE = fmaf(-sk1, mde, cbE); \
    float De = CE * cbE; \
    float cbO = fmaf(-wk, I1o, I0o); cbO = fmaf(-sk1, mdo, cbO); \
    float Do = CE * cbO; \
    float a306o = rdl(c6e, 50); \
    float pve = wshr1(c6o); pve = isL0 ? a3 : pve; \
    float pvo = c6e; \
    float t4e = fmaf(AV0e, pve, fmaf(AV1e, i10e, De)) * (Ca).x; \
    float t5e = c4e * (Ca).y; \
    float t6e = c5e * (Ca).z; \
    float t8e = fmaf(BV0e, pve, BV1e * i10e) * (Cb).x; \
    float t9e = i8e * (Cb).y; \
    float tXe = i9e * (Cb).z; \
    float t4o = fmaf(AV0o, pvo, fmaf(AV1o, i10o, Do)) * (Cc).x; \
    float t5o = c4o * (Cc).y; \
    float t6o = c5o * (Cc).z; \
    float t8o = fmaf(BV0o, pvo, BV1o * i10o) * (Cd).x; \
    float t9o = i8o * (Cd).y; \
    float tXo = i9o * (Cd).z; \
    float n0 = A00 * a0 * (Cs4).x; \
    float n1 = A01 * a0 * (Cs4).y; \
    float n2 = a1 * (Cs4).z; \
    float n3 = a2 * (Cs4).w; \
    float n7 = fmaf(0.5f, a307, a306o) * (Cs2).x; \
    float nB = fmaf(0.5f, a307, a611) * (Cs2).y; \
    c4e = t4e; c5e = t5e; c6e = t6e; i8e = t8e; i9e = t9e; i10e = tXe; \
    c4o = t4o; c5o = t5o; c6o = t6o; i8o = t8o; i9o = t9o; i10o = tXo; \
    a0 = n0; a1 = n1; a2 = n2; a3 = n3; a307 = n7; a611 = nB; \
    float pme = wshr1(c6o); pme = isL0 ? a3 : pme; \
    mde = pme * ize; \
    mdo = c6e * izo; \
    float v0 = mde + mdo; \
    float S = scan_plain(v0); \
    I0o = S; I0e = wshr1(S) + mde; \
    float v1 = fmaf(wk, mde, mdo); \
    float T = scan_atten(v1, q1, q2, q4, q8, fA, fB); \
    I1o = T; I1e = fmaf(wk, wshr1(T), mde); \
  } while (0)

#define RESCALE() do { \
    float prr = ((c4e + c5e) + (c6e + i8e)) + ((i9e + i10e) + (c4o + c5o)) \
              + ((c6o + i8o) + (i9o + i10o)); \
    float spsum = ((a0 + a1) + (a2 + a3)) + (a307 + a611); \
    prr += isL0 ? spsum : 0.f; \
    float ssum = rdl(scan_plain(prr), 63); \
    int exq = ((__float_as_int(ssum) >> 23) & 255) - 127; \
    e_acc += exq; \
    float scq = __int_as_float((127 - exq) << 23); \
    c4e *= scq; c5e *= scq; c6e *= scq; i8e *= scq; i9e *= scq; i10e *= scq; \
    c4o *= scq; c5o *= scq; c6o *= scq; i8o *= scq; i9o *= scq; i10o *= scq; \
    a0 *= scq; a1 *= scq; a2 *= scq; a3 *= scq; a307 *= scq; a611 *= scq; \
    mde *= scq; mdo *= scq; I0e *= scq; I0o *= scq; I1e *= scq; I1o *= scq; \
  } while (0)

#define LOADROW(Ta, Tb, Tc, Td, Ts4, Ts2, obsv) do { \
    int obsc = __builtin_amdgcn_readfirstlane(obsv); \
    const float* Rx = Etp + (size_t)obsc * ROWW; \
    Ta = *(const float4*)(Rx + loff); \
    Tb = *(const float4*)(Rx + loff + 4); \
    Tc = *(const float4*)(Rx + loff + 8); \
    Td = *(const float4*)(Rx + loff + 12); \
    Ts4 = *(const float4*)(Rx + 0); \
    Ts2 = *(const float2*)(Rx + 4); \
  } while (0)

  // ---- prologue: t = 1..7 synchronous ----
  for (int t = 1; t <= 7; ++t) {
    int obp = idsb[t];
    float4 Pa, Pb, Pc, Pd, Ps4; float2 Ps2;
    LOADROW(Pa, Pb, Pc, Pd, Ps4, Ps2, obp);
    STEP_BODY(Pa, Pb, Pc, Pd, Ps4, Ps2);
  }
  RESCALE();

  // ---- main: depth-3 rotating prefetch (A,B,C), groups of 6 ----
  float4 SAa, SAb, SAc, SAd, SAs4; float2 SAs2;
  float4 SBa, SBb, SBc, SBd, SBs4; float2 SBs2;
  float4 SCa, SCb, SCc, SCd, SCs4; float2 SCs2;
  {
    int o8 = idsb[8], o9 = idsb[9], o10 = idsb[10];
    LOADROW(SAa, SAb, SAc, SAd, SAs4, SAs2, o8);
    LOADROW(SBa, SBb, SBc, SBd, SBs4, SBs2, o9);
    LOADROW(SCa, SCb, SCc, SCd, SCs4, SCs2, o10);
  }
  int obA = idsb[11];
  int obB = idsb[12];
  int obC = idsb[13];
  int obD = idsb[14];

  // t = 8 + 6g + k, g in [0,340), k in [0,6): 2040 steps (t=8..2047)
  for (int g = 0; g < 340; ++g) {
    #pragma unroll
    for (int k = 0; k < 6; ++k) {
      if (k % 3 == 0) {
        STEP_BODY(SAa, SAb, SAc, SAd, SAs4, SAs2);
        LOADROW(SAa, SAb, SAc, SAd, SAs4, SAs2, obA);   // row for t+3
      } else if (k % 3 == 1) {
        STEP_BODY(SBa, SBb, SBc, SBd, SBs4, SBs2);
        LOADROW(SBa, SBb, SBc, SBd, SBs4, SBs2, obA);
      } else {
        STEP_BODY(SCa, SCb, SCc, SCd, SCs4, SCs2);
        LOADROW(SCa, SCb, SCc, SCd, SCs4, SCs2, obA);
      }
      obA = obB; obB = obC; obC = obD;
      int tix = 8 + 6 * g + k + 7;                      // t+7
      tix = tix > TLEN - 1 ? TLEN - 1 : tix;
      obD = idsb[tix];
      __builtin_amdgcn_sched_barrier(0);                // keep loads in their step
    }
    if (g != 339) RESCALE();
  }

  // ---- final: ll = e_acc*ln2 + log(sum beta_final) ----
  float prr = ((c4e + c5e) + (c6e + i8e)) + ((i9e + i10e) + (c4o + c5o))
            + ((c6o + i8o) + (i9o + i10o));
  float spsum = ((a0 + a1) + (a2 + a3)) + (a307 + a611);
  prr += isL0 ? spsum : 0.f;
  float ssum_f = rdl(scan_plain(prr), 63);
  double ll = (double)e_acc * 0.6931471805599453 + (double)logf(ssum_f);
  if (L == 0) out[b] = (float)ll;

#undef STEP_BODY
#undef RESCALE
#undef LOADROW
}

// ---------------- launcher ----------------
extern "C" void kernel_launch(void* const* d_in, const int* in_sizes, int n_in,
                              void* d_out, int out_size, void* d_ws, size_t ws_size,
                              hipStream_t stream) {
  const int*   ids = (const int*)d_in[0];
  const float* w   = (const float*)d_in[1];
  const float* ek  = (const float*)d_in[2];
  const float* ik  = (const float*)d_in[3];
  float* ws  = (float*)d_ws;
  float* out = (float*)d_out;

  k_prep<<<1, 128, 0, stream>>>(w, ws);
  k_zr  <<<NECOL, 256, 0, stream>>>(ws);
  k_pi  <<<1, 640, 0, stream>>>(ik, ws);
  k_et  <<<NS, 64, 0, stream>>>(ek, ws);
  k_main<<<BATCH, 64, 0, stream>>>(ids, ws, out);
}

// Round 8
// 428.114 us; speedup vs baseline: 1.0782x; 1.0782x over previous
//
#include <hip/hip_runtime.h>
#include <math.h>

// ---------------- problem constants ----------------
#define NS 612
#define NECOL 216
#define BATCH 32
#define TLEN 2048
#define ROWW 1024                // floats per permuted emission row (4 KB)
#define CE 2.7182818284590452f

// ---------------- ws layout (float offsets) ----------------
#define O_AV0 0
#define O_AV1 128
#define O_BV0 256
#define O_BV1 384
#define O_IZ3 512
#define O_SC  640                // [0]=wk [1]=A00 [2]=A01
#define O_PIP 768                // [1024] permuted softmax(init)
#define O_ET  2048               // [216*1024] permuted E^T rows

typedef float f32x4 __attribute__((ext_vector_type(4)));
typedef int   i32x2 __attribute__((ext_vector_type(2)));

// slot map: lane L holds pair i=2L,2L+1 in 13 floats at row+L*16:
//  f0..f3 = c4e,c5e,c6e,i8e   f4..f7 = i9e,i10e,c4o,c5o
//  f8..f11 = c6o,i8o,i9o,i10o  f12 = special-Et (lanes 51..56 only)
__device__ __forceinline__ int eslot(int s) {
  if (s >= 4 && s <= 306)  { int i = (s - 4) / 3,  r = (s - 4) % 3;
    return (i >> 1) * 16 + (i & 1) * 6 + r; }
  if (s >= 308 && s <= 610){ int i = (s - 308) / 3, r = (s - 308) % 3;
    return (i >> 1) * 16 + (i & 1) * 6 + 3 + r; }
  if (s <= 3)   return (51 + s) * 16 + 12;
  if (s == 307) return 55 * 16 + 12;
  return 56 * 16 + 12;   // s == 611
}

__device__ __forceinline__ float ipowf(float r, int k) {
  float res = 1.f, bse = r;
  #pragma unroll
  for (int q = 0; q < 7; ++q) { if (k & 1) res *= bse; bse *= bse; k >>= 1; }
  return res;
}

// ---------------- DPP helpers ----------------
#define DPPF(x, ctrl, rm) __int_as_float(__builtin_amdgcn_update_dpp(0, __float_as_int(x), (ctrl), (rm), 0xf, true))

__device__ __forceinline__ float scan_plain(float x) {
  x += DPPF(x, 0x111, 0xf);
  x += DPPF(x, 0x112, 0xf);
  x += DPPF(x, 0x114, 0xf);
  x += DPPF(x, 0x118, 0xf);
  x += DPPF(x, 0x142, 0xa);
  x += DPPF(x, 0x143, 0xc);
  return x;
}
__device__ __forceinline__ float scan_atten(float x, float q1, float q2, float q4, float q8,
                                            float fA, float fB) {
  x = fmaf(DPPF(x, 0x111, 0xf), q1, x);
  x = fmaf(DPPF(x, 0x112, 0xf), q2, x);
  x = fmaf(DPPF(x, 0x114, 0xf), q4, x);
  x = fmaf(DPPF(x, 0x118, 0xf), q8, x);
  x = fmaf(DPPF(x, 0x142, 0xa), fA, x);
  x = fmaf(DPPF(x, 0x143, 0xc), fB, x);
  return x;
}
__device__ __forceinline__ float wshr1(float x) { return DPPF(x, 0x138, 0xf); }
__device__ __forceinline__ float rdl(float x, int l) {
  return __int_as_float(__builtin_amdgcn_readlane(__float_as_int(x), l));
}

// ---------------- prep: coefficient tables (math unchanged, verified) -------
__global__ void k_prep(const float* __restrict__ w, float* __restrict__ ws) {
  __shared__ float Gs[101];
  int tid = threadIdx.x;                  // 128
  float wk = w[304];
  if (tid >= 1 && tid <= 100) {
    float p = wk;
    for (int k = 0; k < tid; ++k) p *= wk;
    Gs[tid] = expf(1.f - p);
  }
  if (tid == 0) {
    Gs[0] = 0.f;
    ws[O_SC + 0] = wk;
    float Z0 = expf(1.f - w[0]) + expf(w[0]);
    ws[O_SC + 1] = expf(1.f - w[0]) / Z0;
    ws[O_SC + 2] = expf(w[0]) / Z0;
  }
  __syncthreads();
  if (tid <= 100) {
    float em = expf(w[tid < 100 ? 1 + tid : 202]);
    float ei = expf(w[101 + tid]);
    float z = em + ei;
    for (int d = 1; d <= 100 - tid; ++d) z += Gs[d];
    float ex = expf(w[203 + tid]);
    float es = expf(1.f - w[203 + tid]);
    float z310 = ex + es;
    ws[O_AV0 + tid] = em / z;
    ws[O_BV0 + tid] = ei / z;
    ws[O_AV1 + tid] = ex / z310;
    ws[O_BV1 + tid] = es / z310;
    ws[O_IZ3 + tid] = 1.f / z;
  }
}

__global__ void k_zr(float* __restrict__ ws) {
  float* row = ws + O_ET + (size_t)blockIdx.x * ROWW;
  for (int i = threadIdx.x; i < ROWW; i += 256) row[i] = 0.f;
}

__global__ void k_et(const float* __restrict__ ek, float* __restrict__ ws) {
  float* Etp = ws + O_ET;
  int s = blockIdx.x;
  int lane = threadIdx.x;                 // 64
  int sl = eslot(s);
  float x[4]; float m = -1e30f;
  #pragma unroll
  for (int k = 0; k < 4; ++k) {
    int c = lane + 64 * k;
    x[k] = (c < NECOL) ? ek[s * NECOL + c] : -1e30f;
    m = fmaxf(m, x[k]);
  }
  #pragma unroll
  for (int o = 32; o; o >>= 1) m = fmaxf(m, __shfl_xor(m, o, 64));
  float e[4]; float sum = 0.f;
  #pragma unroll
  for (int k = 0; k < 4; ++k) {
    int c = lane + 64 * k;
    e[k] = (c < NECOL) ? expf(x[k] - m) : 0.f;
    sum += e[k];
  }
  #pragma unroll
  for (int o = 32; o; o >>= 1) sum += __shfl_xor(sum, o, 64);
  float inv = 1.f / sum;
  #pragma unroll
  for (int k = 0; k < 4; ++k) {
    int c = lane + 64 * k;
    if (c < NECOL) Etp[(size_t)c * ROWW + sl] = e[k] * inv;
  }
}

__global__ void k_pi(const float* __restrict__ ik, float* __restrict__ ws) {
  float* pip = ws + O_PIP;
  __shared__ float wm[10], wsm[10];
  int tid = threadIdx.x;                  // 640
  for (int i = tid; i < ROWW; i += 640) pip[i] = 0.f;
  __syncthreads();
  int lane = tid & 63, wid = tid >> 6;
  float x = (tid < NS) ? ik[tid] : -1e30f;
  float m = x;
  #pragma unroll
  for (int o = 32; o; o >>= 1) m = fmaxf(m, __shfl_xor(m, o, 64));
  if (lane == 0) wm[wid] = m;
  __syncthreads();
  float mm = wm[0];
  #pragma unroll
  for (int k = 1; k < 10; ++k) mm = fmaxf(mm, wm[k]);
  float e = (tid < NS) ? expf(x - mm) : 0.f;
  float sacc = e;
  #pragma unroll
  for (int o = 32; o; o >>= 1) sacc += __shfl_xor(sacc, o, 64);
  if (lane == 0) wsm[wid] = sacc;
  __syncthreads();
  float ss = 0.f;
  #pragma unroll
  for (int k = 0; k < 10; ++k) ss += wsm[k];
  if (tid < NS) pip[eslot(tid)] = e / ss;
}

// ---------------- main: one WAVE per sequence; asm-pinned group pipeline ----
__global__ __launch_bounds__(64, 1) void k_main(const int* __restrict__ ids,
                                                const float* __restrict__ ws,
                                                float* __restrict__ out) {
  const int L = threadIdx.x, b = blockIdx.x;
  const int* idsb = ids + b * TLEN;
  const float* Etp = ws + O_ET;
  const float* pip = ws + O_PIP;
  const unsigned long long Et64 = (unsigned long long)Etp;
  const unsigned long long ids64 = (unsigned long long)idsb;
  const int voff = L << 6;                // byte offset of this lane's 16-float slot

  // per-lane coefficients (clamped; invalid lanes neutralized by zero E slots)
  int ie = 2 * L;     if (ie > 100) ie = 100;
  int io = 2 * L + 1; if (io > 100) io = 100;
  float AV0e = ws[O_AV0 + ie], AV1e = ws[O_AV1 + ie];
  float BV0e = ws[O_BV0 + ie], BV1e = ws[O_BV1 + ie];
  float AV0o = ws[O_AV0 + io], AV1o = ws[O_AV1 + io];
  float BV0o = ws[O_BV0 + io], BV1o = ws[O_BV1 + io];
  float ize = (2 * L <= 99)     ? ws[O_IZ3 + 2 * L]     : 0.f;
  float izo = (2 * L + 1 <= 99) ? ws[O_IZ3 + 2 * L + 1] : 0.f;
  float wk  = ws[O_SC + 0], A00 = ws[O_SC + 1], A01 = ws[O_SC + 2];

  // specials in lanes 51..56 = {0,1,2,3,307,611}: new = (k0*pred + k1*self + ext)*Esp
  float k0 = 0.f, k1 = 0.f;
  if (L == 52) k0 = A01;
  else if (L == 53 || L == 54) k0 = 1.f;
  else if (L == 56) k0 = 0.5f;
  if (L == 51) k1 = A00;
  else if (L == 55) k1 = 0.5f;
  else if (L == 56) k1 = 1.f;
  const bool isL0 = (L == 0), isL55 = (L == 55);

  const float sk1 = 1.f - wk;
  const float r2 = wk * wk;
  const float q1 = r2, q2 = q1 * q1, q4 = q2 * q2, q8 = q4 * q4;
  const float fA = ipowf(r2, (L & 15) + 1), fB = ipowf(r2, (L & 31) + 1);

  // ---- t = 0: beta = pi * Et[obs0] ----
  int ob0 = idsb[0];
  {
    // fallthrough into block below
  }
  const float* R0 = Etp + (size_t)ob0 * ROWW;
  f32x4 p0 = *(const f32x4*)(pip + L * 16);
  f32x4 p1 = *(const f32x4*)(pip + L * 16 + 4);
  f32x4 p2 = *(const f32x4*)(pip + L * 16 + 8);
  float p3 = pip[L * 16 + 12];
  f32x4 e0 = *(const f32x4*)(R0 + L * 16);
  f32x4 e1 = *(const f32x4*)(R0 + L * 16 + 4);
  f32x4 e2 = *(const f32x4*)(R0 + L * 16 + 8);
  float e3 = R0[L * 16 + 12];

  float c4e = p0.x * e0.x, c5e = p0.y * e0.y, c6e = p0.z * e0.z, i8e = p0.w * e0.w;
  float i9e = p1.x * e1.x, i10e = p1.y * e1.y, c4o = p1.z * e1.z, c5o = p1.w * e1.w;
  float c6o = p2.x * e2.x, i8o = p2.y * e2.y, i9o = p2.z * e2.z, i10o = p2.w * e2.w;
  float spv = p3 * e3;

  // initial md + scans (feed D at t=1)
  float mde, mdo, I0e, I0o, I1e, I1o;
  {
    float a3v = rdl(spv, 54);
    float pme = isL0 ? a3v : wshr1(c6o);
    mde = pme * ize;
    mdo = c6e * izo;
    float v0s = mde + mdo;
    float S = scan_plain(v0s);
    I0o = S; I0e = wshr1(S) + mde;
    float v1s = fmaf(wk, mde, mdo);
    float T = scan_atten(v1s, q1, q2, q4, q8, fA, fB);
    I1o = T; I1e = fmaf(wk, wshr1(T), mde);
  }

  int e_acc = 0;

#define STEP_BODY(B0, B1, B2, B3) do { \
    float cbE = fmaf(-wk, I1e, I0e); cbE = fmaf(-sk1, mde, cbE); \
    float De = CE * cbE; \
    float cbO = fmaf(-wk, I1o, I0o); cbO = fmaf(-sk1, mdo, cbO); \
    float Do = CE * cbO; \
    float a306o = rdl(c6e, 50); \
    float a3v   = rdl(spv, 54); \
    float pve = isL0 ? a3v : wshr1(c6o); \
    float pvo = c6e; \
    float spred = wshr1(spv); \
    float ext = isL55 ? a306o : 0.f; \
    float t4e = fmaf(AV0e, pve, fmaf(AV1e, i10e, De)) * (B0).x; \
    float t5e = c4e * (B0).y; \
    float t6e = c5e * (B0).z; \
    float t8e = fmaf(BV0e, pve, BV1e * i10e) * (B0).w; \
    float t9e = i8e * (B1).x; \
    float tXe = i9e * (B1).y; \
    float t4o = fmaf(AV0o, pvo, fmaf(AV1o, i10o, Do)) * (B1).z; \
    float t5o = c4o * (B1).w; \
    float t6o = c5o * (B2).x; \
    float t8o = fmaf(BV0o, pvo, BV1o * i10o) * (B2).y; \
    float t9o = i8o * (B2).z; \
    float tXo = i9o * (B2).w; \
    float nsp = fmaf(k0, spred, fmaf(k1, spv, ext)) * (B3); \
    c4e = t4e; c5e = t5e; c6e = t6e; i8e = t8e; i9e = t9e; i10e = tXe; \
    c4o = t4o; c5o = t5o; c6o = t6o; i8o = t8o; i9o = t9o; i10o = tXo; \
    spv = nsp; \
    float a3n = rdl(spv, 54); \
    float pmn = isL0 ? a3n : wshr1(c6o); \
    mde = pmn * ize; \
    mdo = c6e * izo; \
    float v0s = mde + mdo; \
    float S = scan_plain(v0s); \
    I0o = S; I0e = wshr1(S) + mde; \
    float v1s = fmaf(wk, mde, mdo); \
    float T = scan_atten(v1s, q1, q2, q4, q8, fA, fB); \
    I1o = T; I1e = fmaf(wk, wshr1(T), mde); \
  } while (0)

#define RESCALE() do { \
    float prr = ((c4e + c5e) + (c6e + i8e)) + ((i9e + i10e) + (c4o + c5o)) \
              + ((c6o + i8o) + (i9o + i10o)) + spv; \
    float ssum = rdl(scan_plain(prr), 63); \
    int exq = ((__float_as_int(ssum) >> 23) & 255) - 127; \
    e_acc += exq; \
    float scq = __int_as_float((127 - exq) << 23); \
    c4e *= scq; c5e *= scq; c6e *= scq; i8e *= scq; i9e *= scq; i10e *= scq; \
    c4o *= scq; c5o *= scq; c6o *= scq; i8o *= scq; i9o *= scq; i10o *= scq; \
    spv *= scq; \
    mde *= scq; mdo *= scq; I0e *= scq; I0o *= scq; I1e *= scq; I1o *= scq; \
  } while (0)

  // ---- asm load primitives (order-pinned, un-sinkable) ----
#define GLD4(dst, base, off) \
  asm volatile("global_load_dwordx4 %0, %1, %2 offset:" #off \
               : "=v"(dst) : "v"(voff), "s"(base))
#define GLD1(dst, base, off) \
  asm volatile("global_load_dword %0, %1, %2 offset:" #off \
               : "=v"(dst) : "v"(voff), "s"(base))
#define GLD2(dst, base, vo, off) \
  asm volatile("global_load_dwordx2 %0, %1, %2 offset:" #off \
               : "=v"(dst) : "v"(vo), "s"(base))

#define LOADROW(P, obsv) do { \
    unsigned int _oc = (unsigned int)__builtin_amdgcn_readfirstlane(obsv); \
    unsigned long long _ba = Et64 + ((unsigned long long)_oc << 12); \
    GLD4(P##0, _ba, 0); \
    GLD4(P##1, _ba, 16); \
    GLD4(P##2, _ba, 32); \
    GLD1(P##3, _ba, 48); \
  } while (0)

#define LOADOBS(O, tstart) do { \
    int _ts = (tstart); if (_ts > TLEN - 6) _ts = TLEN - 6; \
    int _vo = _ts * 4; \
    GLD2(O##0, ids64, _vo, 0); \
    GLD2(O##1, ids64, _vo, 8); \
    GLD2(O##2, ids64, _vo, 16); \
  } while (0)

  // ---- prologue: t = 1..7 synchronous ----
  for (int t = 1; t <= 7; ++t) {
    int obp = idsb[t];
    const float* Rx = Etp + (size_t)__builtin_amdgcn_readfirstlane(obp) * ROWW;
    f32x4 P0 = *(const f32x4*)(Rx + L * 16);
    f32x4 P1 = *(const f32x4*)(Rx + L * 16 + 4);
    f32x4 P2 = *(const f32x4*)(Rx + L * 16 + 8);
    float P3 = Rx[L * 16 + 12];
    STEP_BODY(P0, P1, P2, P3);
  }
  RESCALE();

  // ---- pipeline buffers ----
  f32x4 Ar00, Ar01, Ar02; float Ar03;
  f32x4 Ar10, Ar11, Ar12; float Ar13;
  f32x4 Ar20, Ar21, Ar22; float Ar23;
  f32x4 Ar30, Ar31, Ar32; float Ar33;
  f32x4 Ar40, Ar41, Ar42; float Ar43;
  f32x4 Ar50, Ar51, Ar52; float Ar53;
  f32x4 Br00, Br01, Br02; float Br03;
  f32x4 Br10, Br11, Br12; float Br13;
  f32x4 Br20, Br21, Br22; float Br23;
  f32x4 Br30, Br31, Br32; float Br33;
  f32x4 Br40, Br41, Br42; float Br43;
  f32x4 Br50, Br51, Br52; float Br53;
  i32x2 OA0, OA1, OA2, OB0, OB1, OB2;

  // fill: obs window group0 -> OA; rows group0 -> A; obs window group1 -> OB
  LOADOBS(OA, 8);
  asm volatile("s_waitcnt vmcnt(0)" ::: "memory");
  __builtin_amdgcn_sched_barrier(0);
  LOADROW(Ar0, OA0.x);
  LOADROW(Ar1, OA0.y);
  LOADROW(Ar2, OA1.x);
  LOADROW(Ar3, OA1.y);
  LOADROW(Ar4, OA2.x);
  LOADROW(Ar5, OA2.y);
  LOADOBS(OB, 14);

#define ITER(C, OC, N, ON, gexp) do { \
    asm volatile("s_waitcnt vmcnt(0)" ::: "memory"); \
    __builtin_amdgcn_sched_barrier(0); \
    LOADROW(N##r0, (OC##0).x); \
    LOADROW(N##r1, (OC##0).y); \
    LOADROW(N##r2, (OC##1).x); \
    LOADROW(N##r3, (OC##1).y); \
    LOADROW(N##r4, (OC##2).x); \
    LOADROW(N##r5, (OC##2).y); \
    LOADOBS(ON, 8 + 6 * ((gexp) + 2)); \
    __builtin_amdgcn_sched_barrier(0); \
    STEP_BODY(C##r00, C##r01, C##r02, C##r03); \
    STEP_BODY(C##r10, C##r11, C##r12, C##r13); \
    STEP_BODY(C##r20, C##r21, C##r22, C##r23); \
    STEP_BODY(C##r30, C##r31, C##r32, C##r33); \
    STEP_BODY(C##r40, C##r41, C##r42, C##r43); \
    STEP_BODY(C##r50, C##r51, C##r52, C##r53); \
    RESCALE(); \
  } while (0)

  // 340 groups of 6 steps: t = 8 .. 2047
  for (int g = 0; g < 340; g += 2) {
    ITER(A, OB, B, OA, g);
    ITER(B, OA, A, OB, g + 1);
  }

  // ---- final: ll = e_acc*ln2 + log(sum beta_final) ----
  float prr = ((c4e + c5e) + (c6e + i8e)) + ((i9e + i10e) + (c4o + c5o))
            + ((c6o + i8o) + (i9o + i10o)) + spv;
  float ssum_f = rdl(scan_plain(prr), 63);
  double ll = (double)e_acc * 0.6931471805599453 + (double)logf(ssum_f);
  if (L == 0) out[b] = (float)ll;

#undef STEP_BODY
#undef RESCALE
#undef GLD4
#undef GLD1
#undef GLD2
#undef LOADROW
#undef LOADOBS
#undef ITER
}

// ---------------- launcher ----------------
extern "C" void kernel_launch(void* const* d_in, const int* in_sizes, int n_in,
                              void* d_out, int out_size, void* d_ws, size_t ws_size,
                              hipStream_t stream) {
  const int*   ids = (const int*)d_in[0];
  const float* w   = (const float*)d_in[1];
  const float* ek  = (const float*)d_in[2];
  const float* ik  = (const float*)d_in[3];
  float* ws  = (float*)d_ws;
  float* out = (float*)d_out;

  k_prep<<<1, 128, 0, stream>>>(w, ws);
  k_zr  <<<NECOL, 256, 0, stream>>>(ws);
  k_pi  <<<1, 640, 0, stream>>>(ik, ws);
  k_et  <<<NS, 64, 0, stream>>>(ek, ws);
  k_main<<<BATCH, 64, 0, stream>>>(ids, ws, out);
}